// Round 1
// 76.939 us; speedup vs baseline: 1.0790x; 1.0790x over previous
//
#include <hip/hip_runtime.h>
#include <hip/hip_bf16.h>

// ROIAlign forward, fp32 in/out. feat: NCHW (2,256,200,304); rois: (1024,5);
// out: [R][C][7][7]. pooled 7x7, grid 2x2, scale 0.25, aligned=True.
//
// v2 strategy (on top of the 83us bf16-NHWC version):
//  - The gather's 411MB of sampled traffic comes from a 62MB map (6.6x line
//    reuse). Random ROI order spreads reuse partners across XCDs/time ->
//    served by Infinity Cache (~8 TB/s) -> ~50us. Fix: bitonic-sort ROIs by
//    (batch, y-band, serpentine x) and give each XCD a contiguous sorted
//    chunk (blockIdx%8 round-robin) so overlapping ROIs run concurrently on
//    the same XCD and reuse hits its 4MB L2 instead of L3.
//  - Sort (1 block, ~3us) is fused into the transpose launch (block 0) so it
//    costs no extra latency.
//  - Transpose vectorized: float4 reads (16B/lane), ushort2 bf16 writes.
//  - Gather inner arithmetic is UNCHANGED (bit-identical outputs; only the
//    block->ROI mapping is permuted).

constexpr int PH = 7;
constexpr int PW = 7;
constexpr float SCALE = 0.25f;
constexpr int LSTRIDE = 258;   // dwords per cell row; %32==2 -> <=2-way on
                               // transposed read; even -> float2 aligned

__device__ __forceinline__ unsigned short f2bf(float f)
{
    unsigned u = __float_as_uint(f);
    // RNE (matches __float2bfloat16 for normal values)
    unsigned r = (u + 0x7fffu + ((u >> 16) & 1u)) >> 16;
    return (unsigned short)r;
}

__device__ __forceinline__ float bf2f(unsigned short u)
{
    return __uint_as_float((unsigned int)u << 16);
}

// ---- fused: block 0 = ROI spatial sort; blocks 1.. = NCHW->NHWC bf16 ------
__global__ __launch_bounds__(256) void prep_kernel(
    const float* __restrict__ in, unsigned short* __restrict__ out,
    const float* __restrict__ rois, int* __restrict__ perm,
    int C, int HW, int tilesC, int tilesP, int R)
{
    __shared__ float tile[64][65];
    __shared__ unsigned skey[1024];

    int bid = blockIdx.x;
    int tid = threadIdx.x;

    if (bid == 0) {
        // ---- bitonic sort of R==1024 ROIs by (batch, y-band, serp-x) ----
        if (perm) {
            for (int i = tid; i < 1024; i += 256) {
                const float* roi = rois + (size_t)i * 5;
                int   b  = (int)roi[0];
                float yc = (roi[2] + roi[4]) * 0.5f * SCALE;
                float xc = (roi[1] + roi[3]) * 0.5f * SCALE;
                int yt = max(0, min(31, ((int)yc) >> 4));
                int xq = max(0, min(4095, (int)xc));
                if (yt & 1) xq = 4095 - xq;      // serpentine within band
                skey[i] = ((unsigned)min(b, 3) << 28) | ((unsigned)yt << 22) |
                          ((unsigned)xq << 10) | (unsigned)i;
            }
            __syncthreads();
            for (int k = 2; k <= 1024; k <<= 1) {
                for (int j = k >> 1; j > 0; j >>= 1) {
                    for (int i = tid; i < 1024; i += 256) {
                        int l = i ^ j;
                        if (l > i) {
                            unsigned a = skey[i], c = skey[l];
                            bool up = ((i & k) == 0);
                            if ((a > c) == up) { skey[i] = c; skey[l] = a; }
                        }
                    }
                    __syncthreads();
                }
            }
            for (int i = tid; i < 1024; i += 256)
                perm[i] = (int)(skey[i] & 1023u);
        }
        return;
    }

    // ---- transpose one 64ch x 64pos tile ----
    int t   = bid - 1;
    int b   = t / (tilesC * tilesP);
    int rem = t - b * (tilesC * tilesP);
    int cy  = rem / tilesP;
    int p0  = (rem - cy * tilesP) * 64;
    int c0  = cy * 64;

    const float*    ib = in  + (size_t)b * (size_t)C * (size_t)HW;
    unsigned short* ob = out + (size_t)b * (size_t)C * (size_t)HW;

    int q  = tid & 15;        // position quad
    int rr = tid >> 4;        // 0..15 (channel row base)
    #pragma unroll
    for (int i = 0; i < 4; ++i) {
        int row = rr + i * 16;
        const float4 v = *(const float4*)(ib + (size_t)(c0 + row) * HW + p0 + q * 4);
        tile[row][q * 4 + 0] = v.x;
        tile[row][q * 4 + 1] = v.y;
        tile[row][q * 4 + 2] = v.z;
        tile[row][q * 4 + 3] = v.w;
    }
    __syncthreads();

    int q2  = tid & 31;       // channel pair index
    int pb  = tid >> 5;       // 0..7
    #pragma unroll
    for (int i = 0; i < 8; ++i) {
        int p = pb + i * 8;   // 0..63
        ushort2 h;
        h.x = f2bf(tile[q2 * 2 + 0][p]);
        h.y = f2bf(tile[q2 * 2 + 1][p]);
        *(ushort2*)(ob + (size_t)(p0 + p) * C + c0 + q2 * 2) = h;
    }
}

// branchless axis interp: clamped indices, validity folded into weights
__device__ __forceinline__ void axis_interp(
    float c, int size, int& lo, int& hi, float& w0, float& w1)
{
    float v  = (c > -1.0f && c < (float)size) ? 1.0f : 0.0f;
    float c0 = fmaxf(c, 0.0f);
    float fl = floorf(c0);
    lo = min((int)fl, size - 1);
    hi = min(lo + 1, size - 1);
    float fr = (fl >= (float)(size - 1)) ? 0.0f : (c0 - (float)lo);
    w1 = fr * v;
    w0 = (1.0f - fr) * v;
}

// ---------------- gather from bf16 NHWC, one block (8 waves) per ROI -------
__global__ __launch_bounds__(512) void roialign_nhwc(
    const unsigned short* __restrict__ nhwc,  // [N][H][W][C] bf16 bits
    const float* __restrict__ rois,           // [R][5]
    const int* __restrict__ perm,             // sorted order or nullptr
    float* __restrict__ out,                  // [R][C][49]
    int C, int H, int W, int R)
{
    __shared__ float lds[49 * LSTRIDE];   // [cell][c]

    int bid = blockIdx.x;
    int r;
    if (perm) {
        // XCD-chunked: blocks with bid%8==k (round-robin to XCD k) process a
        // CONTIGUOUS sorted range -> reuse partners share an L2.
        int chunk = R >> 3;                       // R%8==0 guaranteed by gate
        int s = (bid & 7) * chunk + (bid >> 3);
        r = perm[s];
    } else {
        r = bid;
    }

    int tid  = threadIdx.x;
    int lane = tid & 63;
    int wave = tid >> 6;              // 0..7

    const float* roi = rois + (size_t)r * 5;
    int   b  = (int)roi[0];
    float x1 = roi[1] * SCALE - 0.5f;
    float y1 = roi[2] * SCALE - 0.5f;
    float x2 = roi[3] * SCALE - 0.5f;
    float y2 = roi[4] * SCALE - 0.5f;
    float bw = (x2 - x1) / (float)PW;
    float bh = (y2 - y1) / (float)PH;

    const unsigned short* base = nhwc + (size_t)b * (size_t)H * W * C;
    int coff = lane * 4;              // 4 channels per lane

    for (int cell = wave; cell < PH * PW; cell += 8) {
        int ph = cell / PW;
        int pw = cell - ph * PW;

        // 4 y-entries (gy x corner) and 4 x-entries; samples are the cross.
        int   ys[4], xs[4];
        float wy[4], wx[4];
        {
            float yc0 = y1 + ((float)ph + 0.25f) * bh;
            float yc1 = y1 + ((float)ph + 0.75f) * bh;
            float xc0 = x1 + ((float)pw + 0.25f) * bw;
            float xc1 = x1 + ((float)pw + 0.75f) * bw;
            axis_interp(yc0, H, ys[0], ys[1], wy[0], wy[1]);
            axis_interp(yc1, H, ys[2], ys[3], wy[2], wy[3]);
            axis_interp(xc0, W, xs[0], xs[1], wx[0], wx[1]);
            axis_interp(xc1, W, xs[2], xs[3], wx[2], wx[3]);
        }

        float a0 = 0.f, a1 = 0.f, a2 = 0.f, a3 = 0.f;
        #pragma unroll
        for (int iy = 0; iy < 4; ++iy) {
            #pragma unroll
            for (int ix = 0; ix < 4; ++ix) {
                const ushort4 v = *(const ushort4*)(
                    base + ((size_t)ys[iy] * W + xs[ix]) * C + coff);
                float w = wy[iy] * wx[ix];
                a0 += bf2f(v.x) * w;
                a1 += bf2f(v.y) * w;
                a2 += bf2f(v.z) * w;
                a3 += bf2f(v.w) * w;
            }
        }

        // two 8B LDS stores per lane: <=2-way (free)
        float2* dst = (float2*)(lds + cell * LSTRIDE + coff);
        dst[0] = make_float2(a0 * 0.25f, a1 * 0.25f);
        dst[1] = make_float2(a2 * 0.25f, a3 * 0.25f);
    }
    __syncthreads();

    float* outr = out + (size_t)r * (size_t)C * (PH * PW);
    for (int o = tid; o < C * PH * PW; o += 512) {
        int c    = o / (PH * PW);
        int cell = o - c * (PH * PW);
        outr[o] = lds[cell * LSTRIDE + c];        // bank stride 2 -> <=2-way
    }
}

// ---------------- fallback: thread-per-output NCHW gather ------------------
__global__ __launch_bounds__(256) void roialign_fwd(
    const float* __restrict__ feat, const float* __restrict__ rois,
    float* __restrict__ out, int C, int H, int W, int total)
{
    int idx = blockIdx.x * blockDim.x + threadIdx.x;
    if (idx >= total) return;
    int pw = idx % PW;
    int ph = (idx / PW) % PH;
    int c  = (idx / (PW * PH)) % C;
    int r  = idx / (PW * PH * C);

    const float* roi = rois + (size_t)r * 5;
    int   b  = (int)roi[0];
    float x1 = roi[1] * SCALE - 0.5f;
    float y1 = roi[2] * SCALE - 0.5f;
    float x2 = roi[3] * SCALE - 0.5f;
    float y2 = roi[4] * SCALE - 0.5f;
    float bw = (x2 - x1) / (float)PW;
    float bh = (y2 - y1) / (float)PH;

    const float* plane = feat + ((size_t)b * C + c) * (size_t)H * W;
    float acc = 0.0f;
    #pragma unroll
    for (int gy = 0; gy < 2; ++gy) {
        float yc = y1 + ((float)ph + (gy ? 0.75f : 0.25f)) * bh;
        int yl, yh; float wy0, wy1;
        axis_interp(yc, H, yl, yh, wy0, wy1);
        #pragma unroll
        for (int gx = 0; gx < 2; ++gx) {
            float xc = x1 + ((float)pw + (gx ? 0.75f : 0.25f)) * bw;
            int xl, xh; float wx0, wx1;
            axis_interp(xc, W, xl, xh, wx0, wx1);
            const float* rl = plane + (size_t)yl * W;
            const float* rh = plane + (size_t)yh * W;
            acc += rl[xl] * (wy0 * wx0) + rl[xh] * (wy0 * wx1)
                 + rh[xl] * (wy1 * wx0) + rh[xh] * (wy1 * wx1);
        }
    }
    out[idx] = acc * 0.25f;
}

extern "C" void kernel_launch(void* const* d_in, const int* in_sizes, int n_in,
                              void* d_out, int out_size, void* d_ws, size_t ws_size,
                              hipStream_t stream)
{
    const float* feat = (const float*)d_in[0];
    const float* rois = (const float*)d_in[1];
    float* out = (float*)d_out;

    const int N = 2, C = 256, H = 200, W = 304;
    const int HW = H * W;
    const int R = in_sizes[1] / 5;
    (void)n_in;

    size_t nhwcB = (size_t)N * C * HW * sizeof(unsigned short);
    size_t permB = 1024 * sizeof(int);

    if (ws_size >= nhwcB) {
        unsigned short* nhwc = (unsigned short*)d_ws;
        bool sorted = (R == 1024) && (ws_size >= nhwcB + permB);
        int* perm = sorted ? (int*)((char*)d_ws + nhwcB) : nullptr;

        int tilesP = HW / 64;                 // 950
        int tilesC = C / 64;                  // 4
        int nblk   = N * tilesC * tilesP + 1; // +1: block 0 runs the ROI sort
        prep_kernel<<<nblk, 256, 0, stream>>>(feat, nhwc, rois, perm,
                                              C, HW, tilesC, tilesP, R);
        roialign_nhwc<<<R, 512, 0, stream>>>(nhwc, rois, perm, out, C, H, W, R);
    } else {
        int total = out_size;
        roialign_fwd<<<(total + 255) / 256, 256, 0, stream>>>(feat, rois, out, C, H, W, total);
    }
}